// Round 6
// baseline (2334.848 us; speedup 1.0000x reference)
//
#include <hip/hip_runtime.h>
#include <hip/hip_bf16.h>

#define VOCAB  32000
#define EMBED  512
#define HIDDEN 1024
#define BATCH  16
#define SEQ    256
#define NROW   (BATCH*SEQ)   // 4096 GEMM rows, r = s*16 + b
#define GCOLS  (4*HIDDEN)    // 4096 gate columns, col = g*1024 + j

typedef unsigned short u16;
typedef unsigned int   u32;
typedef unsigned long long u64;
typedef __attribute__((ext_vector_type(4))) float f32x4;
typedef __attribute__((ext_vector_type(8))) short bf16x8;
typedef __attribute__((ext_vector_type(8))) unsigned short u16x8;
typedef __attribute__((ext_vector_type(2))) unsigned long long u64x2;

__device__ inline u16 f2bf(float f){
  __hip_bfloat16 h = __float2bfloat16(f);
  return __builtin_bit_cast(u16, h);
}

__device__ inline void gload_lds16(const void* g, void* l){
  __builtin_amdgcn_global_load_lds((const __attribute__((address_space(1))) u32*)g,
                                   (__attribute__((address_space(3))) u32*)l, 16, 0, 0);
}

// ---------------------------------------------------------------------------
// Pack weights into MFMA B-fragment order: Bp[nblk][kb][lane][e] (ushort bf16)
//   col = nblk*16 + (lane&15), k = kb*32 + (lane>>4)*8 + e
// ---------------------------------------------------------------------------
__global__ __launch_bounds__(256) void pack_kernel(
    const float* __restrict__ Wf, const float* __restrict__ Wi,
    const float* __restrict__ Wc, const float* __restrict__ Wo,
    const float* __restrict__ Wout,
    const float* __restrict__ bf_, const float* __restrict__ bi_,
    const float* __restrict__ bc_, const float* __restrict__ bo_,
    u16* __restrict__ Wxp, u16* __restrict__ Whp, u16* __restrict__ Woutp,
    float* __restrict__ bcat)
{
  const int NT_WX   = (GCOLS/16)*(EMBED/32)*64;   // 262144
  const int NT_WH   = (GCOLS/16)*(HIDDEN/32)*64;  // 524288
  const int NT_WOUT = (VOCAB/16)*(HIDDEN/32)*64;  // 4096000
  int t = blockIdx.x*256 + threadIdx.x;
  if (t < NT_WX){
    int u = t;
    int lane = u&63; int kb = (u>>6)&15; int nblk = u>>10;
    int col = nblk*16 + (lane&15);
    int k0  = kb*32 + ((lane>>4)<<3);
    int g = col>>10, j = col&1023;
    const float* W = (g==0)?Wf:(g==1)?Wi:(g==2)?Wc:Wo;
    u16x8 v;
    #pragma unroll
    for (int e=0;e<8;e++) v[e] = f2bf(W[(size_t)(k0+e)*HIDDEN + j]);
    *(u16x8*)(Wxp + (size_t)u*8) = v;
  } else if (t < NT_WX + NT_WH){
    int u = t - NT_WX;
    int lane = u&63; int kb = (u>>6)&31; int nblk = u>>11;
    int col = nblk*16 + (lane&15);
    int k0  = kb*32 + ((lane>>4)<<3);
    int g = col>>10, j = col&1023;
    const float* W = (g==0)?Wf:(g==1)?Wi:(g==2)?Wc:Wo;
    u16x8 v;
    #pragma unroll
    for (int e=0;e<8;e++) v[e] = f2bf(W[(size_t)(EMBED + k0+e)*HIDDEN + j]);
    *(u16x8*)(Whp + (size_t)u*8) = v;
  } else if (t < NT_WX + NT_WH + NT_WOUT){
    int u = t - NT_WX - NT_WH;
    int lane = u&63; int kb = (u>>6)&31; int nblk = u>>11;
    int col = nblk*16 + (lane&15);
    int k0  = kb*32 + ((lane>>4)<<3);
    u16x8 v;
    #pragma unroll
    for (int e=0;e<8;e++) v[e] = f2bf(Wout[(size_t)(k0+e)*VOCAB + col]);
    *(u16x8*)(Woutp + (size_t)u*8) = v;
  } else {
    int u = t - NT_WX - NT_WH - NT_WOUT;
    if (u < GCOLS){
      int g = u>>10, j = u&1023;
      const float* B = (g==0)?bf_:(g==1)?bi_:(g==2)?bc_:bo_;
      bcat[u] = B[j];
    }
  }
}

// ---------------------------------------------------------------------------
// Embedding gather into MFMA A-fragment order.
// ---------------------------------------------------------------------------
__global__ __launch_bounds__(256) void gather_kernel(
    const int* __restrict__ tok, const float* __restrict__ embed, u16* __restrict__ Xg)
{
  int t = blockIdx.x*256 + threadIdx.x;   // 262144 total
  int lane = t&63; int kb = (t>>6)&15; int mblk = t>>10;
  int s = mblk; int b = lane&15;
  int token = tok[b*SEQ + s];
  int k0 = kb*32 + ((lane>>4)<<3);
  const float* src = embed + (size_t)token*EMBED + k0;
  u16x8 v;
  #pragma unroll
  for (int e=0;e<8;e++) v[e] = f2bf(src[e]);
  *(u16x8*)(Xg + (size_t)t*8) = v;
}

// ---------------------------------------------------------------------------
// 128x128 bf16 GEMM, packed-fragment A and B, m97 2-barrier structure.
// ---------------------------------------------------------------------------
template<int KB, bool REMAP>
__global__ __launch_bounds__(256,2) void gemm_pk(
    const u16* __restrict__ Ap, const u16* __restrict__ Bp,
    const float* __restrict__ bias, float* __restrict__ C,
    int Nblk128, int N)
{
  __shared__ u16 sm[8192];   // A chunks [0,4096), B chunks [4096,8192)
  int tid = threadIdx.x; int lane = tid&63; int wv = tid>>6;
  int nwg = gridDim.x;
  int bid = blockIdx.x;
  int swz = (bid&7)*(nwg>>3) + (bid>>3);   // XCD-aware, bijective (nwg%8==0)
  int bm = swz / Nblk128, bn = swz % Nblk128;
  int wr = wv>>1, wc = wv&1;
  f32x4 acc[4][4] = {};
  const u16* Abase = Ap + (size_t)(bm*8)*KB*512;
  const u16* Bbase = Bp + (size_t)(bn*8)*KB*512;
  for (int kb=0; kb<KB; ++kb){
    __syncthreads();
    #pragma unroll
    for (int c2=0;c2<4;c2++){
      int chunk = wv*4 + c2;
      const u16* g;
      if (chunk < 8) g = Abase + ((size_t)chunk*KB + kb)*512 + lane*8;
      else           g = Bbase + ((size_t)(chunk-8)*KB + kb)*512 + lane*8;
      gload_lds16(g, sm + chunk*512);
    }
    __syncthreads();
    bf16x8 a[4], b[4];
    #pragma unroll
    for (int m=0;m<4;m++) a[m] = *(const bf16x8*)(sm + (wr*4+m)*512 + lane*8);
    #pragma unroll
    for (int n=0;n<4;n++) b[n] = *(const bf16x8*)(sm + 4096 + (wc*4+n)*512 + lane*8);
    #pragma unroll
    for (int m=0;m<4;m++)
      #pragma unroll
      for (int n=0;n<4;n++)
        acc[m][n] = __builtin_amdgcn_mfma_f32_16x16x32_bf16(a[m], b[n], acc[m][n], 0,0,0);
  }
  int colb = bn*128 + wc*64;
  int rowb = bm*128 + wr*64;
  #pragma unroll
  for (int m=0;m<4;m++){
    int row0 = rowb + m*16 + (lane>>4)*4;
    #pragma unroll
    for (int n=0;n<4;n++){
      int col = colb + n*16 + (lane&15);
      float bv = bias[col];
      #pragma unroll
      for (int r2=0;r2<4;r2++){
        int row = row0 + r2;
        int orow = REMAP ? ((row&15)*SEQ + (row>>4)) : row;
        C[(size_t)orow*N + col] = acc[m][n][r2] + bv;
      }
    }
  }
}

// ---------------------------------------------------------------------------
// LSTM recurrence v3. 64 WGs x 256 threads (1 WG/CU, 4 waves).
// Wave v = K-quarter (kc in [v*8, v*8+8)), computing ALL 4 gates:
//   wf[4][8] = 128 VGPR, af[8] = 32 VGPR  -> ~220 total, fits 256 budget.
// NO per-step cache-invalidating fence: h exchanged via HW-coherent relaxed
// agent atomics (bypass L1/L2), so Whp/Xpre stay L2-warm. Sync = single
// release fetch_add counter + per-wave single-lane poll.
// Cross-wave gate reduce via gl[16][16][17] (2-way banks both phases).
// ---------------------------------------------------------------------------
__global__ __launch_bounds__(256,1) __attribute__((amdgpu_waves_per_eu(1,1)))
void lstm_rec(
    const u16* __restrict__ Whp, const float* __restrict__ Xpre,
    u16* hbufs, u16* __restrict__ Hp, u32* cnt)
{
  int tid = threadIdx.x; int lane = tid&63; int v = tid>>6;   // v = K-quarter
  int w = blockIdx.x;               // 0..63 (j-group)
  // wf[g][i]: B-fragment for gate g, kc = v*8+i
  bf16x8 wf[4][8];
  #pragma unroll
  for (int g=0;g<4;g++){
    const u16* wp = Whp + ((size_t)(g*64 + w)*32 + v*8)*512 + lane*8;
    #pragma unroll
    for (int i=0;i<8;i++) wf[g][i] = *(const bf16x8*)(wp + (size_t)i*512);
  }
  __shared__ float gl[16][16][17];   // [m=v*4+g][b][j], padded
  float c = 0.f;
  int pb = tid>>4, pj = tid&15;     // pointwise (batch, local j)
  int j = w*16 + pj;
  const int a_row = lane&15, a_k = (lane>>4)*8;
  // x prefetch for s=0
  const float* xb0 = Xpre + (size_t)pb*GCOLS + j;
  float x0 = xb0[0], x1 = xb0[1024], x2 = xb0[2048], x3 = xb0[3072];
  for (int s=0;s<SEQ;s++){
    const u16* rbuf = hbufs + (s&1)*16384;       // holds h_{s-1}
    u16* wbuf = hbufs + ((s+1)&1)*16384;         // receives h_s
    // A-fragments: HW-coherent loads (bypass L1/L2 -> always fresh, no fence)
    bf16x8 af[8];
    #pragma unroll
    for (int i=0;i<8;i++){
      const u64* p = (const u64*)(rbuf + a_row*1024 + (v*8+i)*32 + a_k);
      u64 lo = __hip_atomic_load(p+0, __ATOMIC_RELAXED, __HIP_MEMORY_SCOPE_AGENT);
      u64 hi = __hip_atomic_load(p+1, __ATOMIC_RELAXED, __HIP_MEMORY_SCOPE_AGENT);
      u64x2 t2 = {lo, hi};
      af[i] = __builtin_bit_cast(bf16x8, t2);
    }
    f32x4 acc[4] = {};
    #pragma unroll
    for (int i=0;i<8;i++){
      #pragma unroll
      for (int g=0;g<4;g++)
        acc[g] = __builtin_amdgcn_mfma_f32_16x16x32_bf16(af[i], wf[g][i], acc[g], 0,0,0);
    }
    {
      int jj = lane&15, b0 = (lane>>4)*4;
      #pragma unroll
      for (int g=0;g<4;g++)
        #pragma unroll
        for (int r2=0;r2<4;r2++)
          gl[v*4+g][b0+r2][jj] = acc[g][r2];
    }
    __syncthreads();                               // B1
    float p0 = x0 + gl[0][pb][pj] + gl[4][pb][pj] + gl[ 8][pb][pj] + gl[12][pb][pj];
    float p1 = x1 + gl[1][pb][pj] + gl[5][pb][pj] + gl[ 9][pb][pj] + gl[13][pb][pj];
    float p2 = x2 + gl[2][pb][pj] + gl[6][pb][pj] + gl[10][pb][pj] + gl[14][pb][pj];
    float p3 = x3 + gl[3][pb][pj] + gl[7][pb][pj] + gl[11][pb][pj] + gl[15][pb][pj];
    float fg = 1.f/(1.f+__expf(-p0));
    float ig = 1.f/(1.f+__expf(-p1));
    float e2 = __expf(2.f*fminf(fmaxf(p2,-15.f),15.f));
    float cand = (e2-1.f)/(e2+1.f);
    float og = 1.f/(1.f+__expf(-p3));
    c = c*fg + cand*ig;
    float h = c*og;                  // reference: h = c * o (no tanh on c)
    // prefetch next step's x (read-only, safe to issue pre-poll)
    if (s < SEQ-1){
      const float* xn = Xpre + ((size_t)(s+1)*16 + pb)*GCOLS + j;
      x0 = xn[0]; x1 = xn[1024]; x2 = xn[2048]; x3 = xn[3072];
    }
    // pair-pack h via shfl (pj even lane takes pj|pj+1), store as u32
    u32 hb = (u32)f2bf(h);
    u32 ob = (u32)__shfl_xor((int)hb, 1);
    if ((pj&1)==0){
      u32 word = hb | (ob<<16);
      if (s < SEQ-1)
        __hip_atomic_store((u32*)wbuf + (size_t)pb*512 + w*8 + (pj>>1), word,
                           __ATOMIC_RELAXED, __HIP_MEMORY_SCOPE_AGENT);
      // Hp (A-fragment packed): u16 idx = s*16384 + (j>>5)*512 + (((j>>3)&3)*16+pb)*8 + (j&7)
      ((u32*)Hp)[(size_t)s*8192 + (size_t)(j>>5)*256
                 + (size_t)(((j>>3)&3)*16 + pb)*4 + ((j&7)>>1)] = word;
    }
    __syncthreads();                               // B2 (drains all waves' stores)
    if (s < SEQ-1){
      if (tid==0)
        (void)__hip_atomic_fetch_add(cnt, 1u, __ATOMIC_RELEASE, __HIP_MEMORY_SCOPE_AGENT);
      if (lane==0){
        u32 tgt = 64u*(u32)(s+1);
        while (__hip_atomic_load(cnt, __ATOMIC_RELAXED, __HIP_MEMORY_SCOPE_AGENT) < tgt) { }
      }
      asm volatile("" ::: "memory");   // compiler ordering only; no cache inv
    }
  }
}

// ---------------------------------------------------------------------------
extern "C" void kernel_launch(void* const* d_in, const int* in_sizes, int n_in,
                              void* d_out, int out_size, void* d_ws, size_t ws_size,
                              hipStream_t stream)
{
  (void)in_sizes; (void)n_in; (void)out_size; (void)ws_size;
  const int*   tok   = (const int*)d_in[0];
  const float* embed = (const float*)d_in[1];
  const float* Wf    = (const float*)d_in[2];
  const float* bf_   = (const float*)d_in[3];
  const float* Wi    = (const float*)d_in[4];
  const float* bi_   = (const float*)d_in[5];
  const float* Wc    = (const float*)d_in[6];
  const float* bc_   = (const float*)d_in[7];
  const float* Wo    = (const float*)d_in[8];
  const float* bo_   = (const float*)d_in[9];
  const float* Wout  = (const float*)d_in[10];
  const float* bout  = (const float*)d_in[11];
  float* out = (float*)d_out;

  char* ws = (char*)d_ws;
  size_t off = 0;
  auto alloc = [&](size_t bytes)->void*{
    void* p = ws + off; off += (bytes + 255) & ~(size_t)255; return p;
  };
  u16*  Wxp   = (u16*)alloc((size_t)2097152*2);
  u16*  Whp   = (u16*)alloc((size_t)4194304*2);
  u16*  Woutp = (u16*)alloc((size_t)32768000*2);
  float* bcat = (float*)alloc((size_t)4096*4);
  u16*  Xg    = (u16*)alloc((size_t)2097152*2);
  float* Xpre = (float*)alloc((size_t)NROW*GCOLS*4);   // 64 MB
  u16*  Hp    = (u16*)alloc((size_t)4194304*2);
  u16*  hbufs = (u16*)alloc((size_t)2*16384*2);        // 64 KB (two h buffers)
  u32*  cnt   = (u32*)alloc((size_t)256);              // step counter

  (void)hipMemsetAsync(hbufs, 0, 2*16384*2 + 256, stream);

  pack_kernel<<<19088, 256, 0, stream>>>(Wf,Wi,Wc,Wo,Wout, bf_,bi_,bc_,bo_,
                                         Wxp, Whp, Woutp, bcat);
  gather_kernel<<<1024, 256, 0, stream>>>(tok, embed, Xg);
  gemm_pk<16,false><<<1024, 256, 0, stream>>>(Xg, Wxp, bcat, Xpre, 32, GCOLS);
  lstm_rec<<<64, 256, 0, stream>>>(Whp, Xpre, hbufs, Hp, cnt);
  gemm_pk<32,true><<<8000, 256, 0, stream>>>(Hp, Woutp, bout, out, 250, VOCAB);
}

// Round 7
// 1501.795 us; speedup vs baseline: 1.5547x; 1.5547x over previous
//
#include <hip/hip_runtime.h>
#include <hip/hip_bf16.h>

#define VOCAB  32000
#define EMBED  512
#define HIDDEN 1024
#define BATCH  16
#define SEQ    256
#define NROW   (BATCH*SEQ)   // 4096 GEMM rows, r = s*16 + b
#define GCOLS  (4*HIDDEN)    // 4096 gate columns, col = g*1024 + j
#define NWREC  64            // recurrence WGs
#define NWPACK 192           // Wout-pack WGs riding in lstm_rec's grid

typedef unsigned short u16;
typedef unsigned int   u32;
typedef unsigned long long u64;
typedef __attribute__((ext_vector_type(4))) float f32x4;
typedef __attribute__((ext_vector_type(8))) short bf16x8;
typedef __attribute__((ext_vector_type(8))) unsigned short u16x8;
typedef __attribute__((ext_vector_type(2))) unsigned long long u64x2;

__device__ inline u16 f2bf(float f){
  __hip_bfloat16 h = __float2bfloat16(f);
  return __builtin_bit_cast(u16, h);
}

__device__ inline void gload_lds16(const void* g, void* l){
  __builtin_amdgcn_global_load_lds((const __attribute__((address_space(1))) u32*)g,
                                   (__attribute__((address_space(3))) u32*)l, 16, 0, 0);
}

// ---------------------------------------------------------------------------
// Pack gate weights into MFMA B-fragment order: Bp[nblk][kb][lane][e]
//   col = nblk*16 + (lane&15), k = kb*32 + (lane>>4)*8 + e
// (Wout packing now lives in lstm_rec's extra WGs.)
// ---------------------------------------------------------------------------
__global__ __launch_bounds__(256) void pack_gates(
    const float* __restrict__ Wf, const float* __restrict__ Wi,
    const float* __restrict__ Wc, const float* __restrict__ Wo,
    const float* __restrict__ bf_, const float* __restrict__ bi_,
    const float* __restrict__ bc_, const float* __restrict__ bo_,
    u16* __restrict__ Wxp, u16* __restrict__ Whp, float* __restrict__ bcat)
{
  const int NT_WX = (GCOLS/16)*(EMBED/32)*64;   // 262144
  const int NT_WH = (GCOLS/16)*(HIDDEN/32)*64;  // 524288
  int t = blockIdx.x*256 + threadIdx.x;
  if (t < NT_WX){
    int u = t;
    int lane = u&63; int kb = (u>>6)&15; int nblk = u>>10;
    int col = nblk*16 + (lane&15);
    int k0  = kb*32 + ((lane>>4)<<3);
    int g = col>>10, j = col&1023;
    const float* W = (g==0)?Wf:(g==1)?Wi:(g==2)?Wc:Wo;
    u16x8 v;
    #pragma unroll
    for (int e=0;e<8;e++) v[e] = f2bf(W[(size_t)(k0+e)*HIDDEN + j]);
    *(u16x8*)(Wxp + (size_t)u*8) = v;
  } else if (t < NT_WX + NT_WH){
    int u = t - NT_WX;
    int lane = u&63; int kb = (u>>6)&31; int nblk = u>>11;
    int col = nblk*16 + (lane&15);
    int k0  = kb*32 + ((lane>>4)<<3);
    int g = col>>10, j = col&1023;
    const float* W = (g==0)?Wf:(g==1)?Wi:(g==2)?Wc:Wo;
    u16x8 v;
    #pragma unroll
    for (int e=0;e<8;e++) v[e] = f2bf(W[(size_t)(EMBED + k0+e)*HIDDEN + j]);
    *(u16x8*)(Whp + (size_t)u*8) = v;
  } else {
    int u = t - NT_WX - NT_WH;
    if (u < GCOLS){
      int g = u>>10, j = u&1023;
      const float* B = (g==0)?bf_:(g==1)?bi_:(g==2)?bc_:bo_;
      bcat[u] = B[j];
    }
  }
}

// ---------------------------------------------------------------------------
// Embedding gather into MFMA A-fragment order.
// ---------------------------------------------------------------------------
__global__ __launch_bounds__(256) void gather_kernel(
    const int* __restrict__ tok, const float* __restrict__ embed, u16* __restrict__ Xg)
{
  int t = blockIdx.x*256 + threadIdx.x;   // 262144 total
  int lane = t&63; int kb = (t>>6)&15; int mblk = t>>10;
  int s = mblk; int b = lane&15;
  int token = tok[b*SEQ + s];
  int k0 = kb*32 + ((lane>>4)<<3);
  const float* src = embed + (size_t)token*EMBED + k0;
  u16x8 v;
  #pragma unroll
  for (int e=0;e<8;e++) v[e] = f2bf(src[e]);
  *(u16x8*)(Xg + (size_t)t*8) = v;
}

// ---------------------------------------------------------------------------
// 128x128 bf16 GEMM, packed-fragment A and B, m97 2-barrier structure.
// ---------------------------------------------------------------------------
template<int KB, bool REMAP>
__global__ __launch_bounds__(256,2) void gemm_pk(
    const u16* __restrict__ Ap, const u16* __restrict__ Bp,
    const float* __restrict__ bias, float* __restrict__ C,
    int Nblk128, int N)
{
  __shared__ u16 sm[8192];   // A chunks [0,4096), B chunks [4096,8192)
  int tid = threadIdx.x; int lane = tid&63; int wv = tid>>6;
  int nwg = gridDim.x;
  int bid = blockIdx.x;
  int swz = (bid&7)*(nwg>>3) + (bid>>3);   // XCD-aware, bijective (nwg%8==0)
  int bm = swz / Nblk128, bn = swz % Nblk128;
  int wr = wv>>1, wc = wv&1;
  f32x4 acc[4][4] = {};
  const u16* Abase = Ap + (size_t)(bm*8)*KB*512;
  const u16* Bbase = Bp + (size_t)(bn*8)*KB*512;
  for (int kb=0; kb<KB; ++kb){
    __syncthreads();
    #pragma unroll
    for (int c2=0;c2<4;c2++){
      int chunk = wv*4 + c2;
      const u16* g;
      if (chunk < 8) g = Abase + ((size_t)chunk*KB + kb)*512 + lane*8;
      else           g = Bbase + ((size_t)(chunk-8)*KB + kb)*512 + lane*8;
      gload_lds16(g, sm + chunk*512);
    }
    __syncthreads();
    bf16x8 a[4], b[4];
    #pragma unroll
    for (int m=0;m<4;m++) a[m] = *(const bf16x8*)(sm + (wr*4+m)*512 + lane*8);
    #pragma unroll
    for (int n=0;n<4;n++) b[n] = *(const bf16x8*)(sm + 4096 + (wc*4+n)*512 + lane*8);
    #pragma unroll
    for (int m=0;m<4;m++)
      #pragma unroll
      for (int n=0;n<4;n++)
        acc[m][n] = __builtin_amdgcn_mfma_f32_16x16x32_bf16(a[m], b[n], acc[m][n], 0,0,0);
  }
  int colb = bn*128 + wc*64;
  int rowb = bm*128 + wr*64;
  #pragma unroll
  for (int m=0;m<4;m++){
    int row0 = rowb + m*16 + (lane>>4)*4;
    #pragma unroll
    for (int n=0;n<4;n++){
      int col = colb + n*16 + (lane&15);
      float bv = bias[col];
      #pragma unroll
      for (int r2=0;r2<4;r2++){
        int row = row0 + r2;
        int orow = REMAP ? ((row&15)*SEQ + (row>>4)) : row;
        C[(size_t)orow*N + col] = acc[m][n][r2] + bv;
      }
    }
  }
}

// ---------------------------------------------------------------------------
// LSTM recurrence v4 + fused Wout pack.
// WGs 0..63: recurrence. 64 WGs x 256 thr (1 WG/CU). Wave v = K-quarter,
//   computing all 4 gates. Wh slice (128KB) LDS-resident (staged once via
//   global_load_lds) -> deterministic, no allocator remat.
//   Sync per step: relaxed-atomic h stores -> vmcnt(0)+syncthreads (drain) ->
//   ONE relaxed flag store per WG (own 128B line) -> wave0 polls all 64 flags
//   with a single 64-lane vector load + s_sleep. NO release/acquire/fence,
//   NO contended RMW -> no cache maintenance, caches stay warm.
// WGs 64..255: pack Wout into MFMA B-fragment order on idle CUs (no sync).
// ---------------------------------------------------------------------------
__global__ __launch_bounds__(256,1) void lstm_rec(
    const u16* __restrict__ Whp, const float* __restrict__ Xpre,
    u16* hbufs, u16* __restrict__ Hp, u32* flags,
    const float* __restrict__ Wout, u16* __restrict__ Woutp)
{
  int tid = threadIdx.x; int lane = tid&63; int v = tid>>6;   // v = wave
  int w = blockIdx.x;

  if (w >= NWREC){
    // ---- Wout pack on idle CUs (no interaction with recurrence) ----
    const int NPK = (VOCAB/16)*(HIDDEN/32)*64;   // 4,096,000
    int u0 = (w - NWREC)*256 + tid;
    for (int u = u0; u < NPK; u += NWPACK*256){
      int l = u&63; int kb = (u>>6)&31; int nblk = u>>11;
      int col = nblk*16 + (l&15);
      int k0  = kb*32 + ((l>>4)<<3);
      u16x8 vv;
      #pragma unroll
      for (int e=0;e<8;e++) vv[e] = f2bf(Wout[(size_t)(k0+e)*VOCAB + col]);
      *(u16x8*)(Woutp + (size_t)u*8) = vv;
    }
    return;
  }

  // ---- recurrence WG ----
  __shared__ u16 smWf[65536];        // 128KB: frag = g*32+kc, [frag][512]
  __shared__ float gl[16][16][17];   // [v*4+g][b][j]

  // stage Wh slice once: wave v stages frags [v*32, v*32+32)
  #pragma unroll
  for (int f=0; f<32; ++f){
    int frag = v*32 + f;
    int g = frag>>5, kc = frag&31;
    const u16* src = Whp + ((size_t)(g*64 + w)*32 + kc)*512 + lane*8;
    gload_lds16(src, smWf + (size_t)frag*512);
  }
  asm volatile("s_waitcnt vmcnt(0)" ::: "memory");
  __syncthreads();

  float c = 0.f;
  int pb = tid>>4, pj = tid&15;     // pointwise (batch, local j)
  int j = w*16 + pj;
  const int a_row = lane&15, a_k = (lane>>4)*8;
  // x prefetch for s=0
  const float* xb0 = Xpre + (size_t)pb*GCOLS + j;
  float x0 = xb0[0], x1 = xb0[1024], x2 = xb0[2048], x3 = xb0[3072];

  for (int s=0;s<SEQ;s++){
    const u16* rbuf = hbufs + (s&1)*16384;       // holds h_{s-1}
    u16* wbuf = hbufs + ((s+1)&1)*16384;         // receives h_s
    // A-fragments: uncached (atomic relaxed) loads -> always fresh, no fence
    bf16x8 af[8];
    #pragma unroll
    for (int i=0;i<8;i++){
      const u64* p = (const u64*)(rbuf + a_row*1024 + (v*8+i)*32 + a_k);
      u64 lo = __hip_atomic_load(p+0, __ATOMIC_RELAXED, __HIP_MEMORY_SCOPE_AGENT);
      u64 hi = __hip_atomic_load(p+1, __ATOMIC_RELAXED, __HIP_MEMORY_SCOPE_AGENT);
      u64x2 t2 = {lo, hi};
      af[i] = __builtin_bit_cast(bf16x8, t2);
    }
    f32x4 acc[4] = {};
    #pragma unroll
    for (int i=0;i<8;i++){
      #pragma unroll
      for (int g=0;g<4;g++){
        bf16x8 wfv = *(const bf16x8*)(smWf + ((size_t)(g*32 + v*8 + i))*512 + lane*8);
        acc[g] = __builtin_amdgcn_mfma_f32_16x16x32_bf16(af[i], wfv, acc[g], 0,0,0);
      }
    }
    {
      int jj = lane&15, b0 = (lane>>4)*4;
      #pragma unroll
      for (int g=0;g<4;g++)
        #pragma unroll
        for (int r2=0;r2<4;r2++)
          gl[v*4+g][b0+r2][jj] = acc[g][r2];
    }
    __syncthreads();                               // B1
    float p0 = x0 + gl[0][pb][pj] + gl[4][pb][pj] + gl[ 8][pb][pj] + gl[12][pb][pj];
    float p1 = x1 + gl[1][pb][pj] + gl[5][pb][pj] + gl[ 9][pb][pj] + gl[13][pb][pj];
    float p2 = x2 + gl[2][pb][pj] + gl[6][pb][pj] + gl[10][pb][pj] + gl[14][pb][pj];
    float p3 = x3 + gl[3][pb][pj] + gl[7][pb][pj] + gl[11][pb][pj] + gl[15][pb][pj];
    float fg = 1.f/(1.f+__expf(-p0));
    float ig = 1.f/(1.f+__expf(-p1));
    float e2 = __expf(2.f*fminf(fmaxf(p2,-15.f),15.f));
    float cand = (e2-1.f)/(e2+1.f);
    float og = 1.f/(1.f+__expf(-p3));
    c = c*fg + cand*ig;
    float h = c*og;                  // reference: h = c * o (no tanh on c)
    // prefetch next step's x (read-only; overlaps barrier wait)
    if (s < SEQ-1){
      const float* xn = Xpre + ((size_t)(s+1)*16 + pb)*GCOLS + j;
      x0 = xn[0]; x1 = xn[1024]; x2 = xn[2048]; x3 = xn[3072];
    }
    // pair-pack h via shfl, store as u32
    u32 hb = (u32)f2bf(h);
    u32 ob = (u32)__shfl_xor((int)hb, 1);
    if ((pj&1)==0){
      u32 word = hb | (ob<<16);
      if (s < SEQ-1)
        __hip_atomic_store((u32*)wbuf + (size_t)pb*512 + w*8 + (pj>>1), word,
                           __ATOMIC_RELAXED, __HIP_MEMORY_SCOPE_AGENT);
      // Hp: normal store (read only after kernel end)
      ((u32*)Hp)[(size_t)s*8192 + (size_t)(j>>5)*256
                 + (size_t)(((j>>3)&3)*16 + pb)*4 + ((j&7)>>1)] = word;
    }
    if (s < SEQ-1){
      asm volatile("s_waitcnt vmcnt(0)" ::: "memory");  // own stores landed
      __syncthreads();                             // B2: all WG stores landed
      if (tid==0)
        __hip_atomic_store(flags + (size_t)w*32, (u32)(s+1),
                           __ATOMIC_RELAXED, __HIP_MEMORY_SCOPE_AGENT);
      if (v==0){
        u32 tgt = (u32)(s+1);
        while (true){
          u32 fv = __hip_atomic_load(flags + (size_t)lane*32,
                                     __ATOMIC_RELAXED, __HIP_MEMORY_SCOPE_AGENT);
          if (__all(fv >= tgt)) break;
          __builtin_amdgcn_s_sleep(1);
        }
      }
      __syncthreads();                             // B3
      asm volatile("" ::: "memory");               // keep af loads below poll
    }
  }
}

// ---------------------------------------------------------------------------
extern "C" void kernel_launch(void* const* d_in, const int* in_sizes, int n_in,
                              void* d_out, int out_size, void* d_ws, size_t ws_size,
                              hipStream_t stream)
{
  (void)in_sizes; (void)n_in; (void)out_size; (void)ws_size;
  const int*   tok   = (const int*)d_in[0];
  const float* embed = (const float*)d_in[1];
  const float* Wf    = (const float*)d_in[2];
  const float* bf_   = (const float*)d_in[3];
  const float* Wi    = (const float*)d_in[4];
  const float* bi_   = (const float*)d_in[5];
  const float* Wc    = (const float*)d_in[6];
  const float* bc_   = (const float*)d_in[7];
  const float* Wo    = (const float*)d_in[8];
  const float* bo_   = (const float*)d_in[9];
  const float* Wout  = (const float*)d_in[10];
  const float* bout  = (const float*)d_in[11];
  float* out = (float*)d_out;

  char* ws = (char*)d_ws;
  size_t off = 0;
  auto alloc = [&](size_t bytes)->void*{
    void* p = ws + off; off += (bytes + 255) & ~(size_t)255; return p;
  };
  u16*  Wxp   = (u16*)alloc((size_t)2097152*2);
  u16*  Whp   = (u16*)alloc((size_t)4194304*2);
  u16*  Woutp = (u16*)alloc((size_t)32768000*2);
  float* bcat = (float*)alloc((size_t)4096*4);
  u16*  Xg    = (u16*)alloc((size_t)2097152*2);
  float* Xpre = (float*)alloc((size_t)NROW*GCOLS*4);   // 64 MB
  u16*  Hp    = (u16*)alloc((size_t)4194304*2);
  u16*  hbufs = (u16*)alloc((size_t)2*16384*2);        // 64 KB (two h buffers)
  u32*  flags = (u32*)alloc((size_t)64*128);           // 128B/flag line

  (void)hipMemsetAsync(hbufs, 0, 2*16384*2 + 64*128, stream);

  pack_gates<<<3088, 256, 0, stream>>>(Wf,Wi,Wc,Wo, bf_,bi_,bc_,bo_,
                                       Wxp, Whp, bcat);
  gather_kernel<<<1024, 256, 0, stream>>>(tok, embed, Xg);
  gemm_pk<16,false><<<1024, 256, 0, stream>>>(Xg, Wxp, bcat, Xpre, 32, GCOLS);
  lstm_rec<<<NWREC+NWPACK, 256, 0, stream>>>(Whp, Xpre, hbufs, Hp, flags,
                                             Wout, Woutp);
  gemm_pk<32,true><<<8000, 256, 0, stream>>>(Hp, Woutp, bout, out, 250, VOCAB);
}

// Round 8
// 1249.510 us; speedup vs baseline: 1.8686x; 1.2019x over previous
//
#include <hip/hip_runtime.h>
#include <hip/hip_bf16.h>

#define VOCAB  32000
#define EMBED  512
#define HIDDEN 1024
#define BATCH  16
#define SEQ    256
#define NROW   (BATCH*SEQ)   // 4096 GEMM rows, r = s*16 + b
#define GCOLS  (4*HIDDEN)    // 4096 gate columns, col = g*1024 + j
#define NWREC  64            // recurrence WGs
#define NWPACK 192           // pack->gemm worker WGs
#define NTILE  8000          // logits tiles: 32 bm x 250 bn
#define SENT32 0xFFFFFFFFu

typedef unsigned short u16;
typedef unsigned int   u32;
typedef unsigned long long u64;
typedef __attribute__((ext_vector_type(4))) float f32x4;
typedef __attribute__((ext_vector_type(8))) short bf16x8;
typedef __attribute__((ext_vector_type(8))) unsigned short u16x8;
typedef __attribute__((ext_vector_type(2))) unsigned long long u64x2;

__device__ inline u16 f2bf(float f){
  __hip_bfloat16 h = __float2bfloat16(f);
  return __builtin_bit_cast(u16, h);
}
__device__ inline void gload_lds16(const void* g, void* l){
  __builtin_amdgcn_global_load_lds((const __attribute__((address_space(1))) u32*)g,
                                   (__attribute__((address_space(3))) u32*)l, 16, 0, 0);
}
__device__ __forceinline__ u32 al32(const u32* p){
  return __hip_atomic_load(p, __ATOMIC_RELAXED, __HIP_MEMORY_SCOPE_AGENT);
}
__device__ __forceinline__ u64 al64(const u64* p){
  return __hip_atomic_load(p, __ATOMIC_RELAXED, __HIP_MEMORY_SCOPE_AGENT);
}
__device__ __forceinline__ void as32(u32* p, u32 v){
  __hip_atomic_store(p, v, __ATOMIC_RELAXED, __HIP_MEMORY_SCOPE_AGENT);
}
__device__ __forceinline__ void as64(u64* p, u64 v){
  __hip_atomic_store(p, v, __ATOMIC_RELAXED, __HIP_MEMORY_SCOPE_AGENT);
}

// ---------------------------------------------------------------------------
// Pack gate weights into MFMA B-fragment order.
// ---------------------------------------------------------------------------
__global__ __launch_bounds__(256) void pack_gates(
    const float* __restrict__ Wf, const float* __restrict__ Wi,
    const float* __restrict__ Wc, const float* __restrict__ Wo,
    const float* __restrict__ bf_, const float* __restrict__ bi_,
    const float* __restrict__ bc_, const float* __restrict__ bo_,
    u16* __restrict__ Wxp, u16* __restrict__ Whp, float* __restrict__ bcat)
{
  const int NT_WX = (GCOLS/16)*(EMBED/32)*64;   // 262144
  const int NT_WH = (GCOLS/16)*(HIDDEN/32)*64;  // 524288
  int t = blockIdx.x*256 + threadIdx.x;
  if (t < NT_WX){
    int u = t;
    int lane = u&63; int kb = (u>>6)&15; int nblk = u>>10;
    int col = nblk*16 + (lane&15);
    int k0  = kb*32 + ((lane>>4)<<3);
    int g = col>>10, j = col&1023;
    const float* W = (g==0)?Wf:(g==1)?Wi:(g==2)?Wc:Wo;
    u16x8 v;
    #pragma unroll
    for (int e=0;e<8;e++) v[e] = f2bf(W[(size_t)(k0+e)*HIDDEN + j]);
    *(u16x8*)(Wxp + (size_t)u*8) = v;
  } else if (t < NT_WX + NT_WH){
    int u = t - NT_WX;
    int lane = u&63; int kb = (u>>6)&31; int nblk = u>>11;
    int col = nblk*16 + (lane&15);
    int k0  = kb*32 + ((lane>>4)<<3);
    int g = col>>10, j = col&1023;
    const float* W = (g==0)?Wf:(g==1)?Wi:(g==2)?Wc:Wo;
    u16x8 v;
    #pragma unroll
    for (int e=0;e<8;e++) v[e] = f2bf(W[(size_t)(EMBED + k0+e)*HIDDEN + j]);
    *(u16x8*)(Whp + (size_t)u*8) = v;
  } else {
    int u = t - NT_WX - NT_WH;
    if (u < GCOLS){
      int g = u>>10, j = u&1023;
      const float* B = (g==0)?bf_:(g==1)?bi_:(g==2)?bc_:bo_;
      bcat[u] = B[j];
    }
  }
}

// ---------------------------------------------------------------------------
// Embedding gather into MFMA A-fragment order.
// ---------------------------------------------------------------------------
__global__ __launch_bounds__(256) void gather_kernel(
    const int* __restrict__ tok, const float* __restrict__ embed, u16* __restrict__ Xg)
{
  int t = blockIdx.x*256 + threadIdx.x;   // 262144 total
  int lane = t&63; int kb = (t>>6)&15; int mblk = t>>10;
  int s = mblk; int b = lane&15;
  int token = tok[b*SEQ + s];
  int k0 = kb*32 + ((lane>>4)<<3);
  const float* src = embed + (size_t)token*EMBED + k0;
  u16x8 v;
  #pragma unroll
  for (int e=0;e<8;e++) v[e] = f2bf(src[e]);
  *(u16x8*)(Xg + (size_t)t*8) = v;
}

// ---------------------------------------------------------------------------
// 128x128 bf16 GEMM (used only for the X-precompute now).
// ---------------------------------------------------------------------------
template<int KB, bool REMAP>
__global__ __launch_bounds__(256,2) void gemm_pk(
    const u16* __restrict__ Ap, const u16* __restrict__ Bp,
    const float* __restrict__ bias, float* __restrict__ C,
    int Nblk128, int N)
{
  __shared__ u16 sm[8192];
  int tid = threadIdx.x; int lane = tid&63; int wv = tid>>6;
  int nwg = gridDim.x;
  int bid = blockIdx.x;
  int swz = (bid&7)*(nwg>>3) + (bid>>3);
  int bm = swz / Nblk128, bn = swz % Nblk128;
  int wr = wv>>1, wc = wv&1;
  f32x4 acc[4][4] = {};
  const u16* Abase = Ap + (size_t)(bm*8)*KB*512;
  const u16* Bbase = Bp + (size_t)(bn*8)*KB*512;
  for (int kb=0; kb<KB; ++kb){
    __syncthreads();
    #pragma unroll
    for (int c2=0;c2<4;c2++){
      int chunk = wv*4 + c2;
      const u16* g;
      if (chunk < 8) g = Abase + ((size_t)chunk*KB + kb)*512 + lane*8;
      else           g = Bbase + ((size_t)(chunk-8)*KB + kb)*512 + lane*8;
      gload_lds16(g, sm + chunk*512);
    }
    __syncthreads();
    bf16x8 a[4], b[4];
    #pragma unroll
    for (int m=0;m<4;m++) a[m] = *(const bf16x8*)(sm + (wr*4+m)*512 + lane*8);
    #pragma unroll
    for (int n=0;n<4;n++) b[n] = *(const bf16x8*)(sm + 4096 + (wc*4+n)*512 + lane*8);
    #pragma unroll
    for (int m=0;m<4;m++)
      #pragma unroll
      for (int n=0;n<4;n++)
        acc[m][n] = __builtin_amdgcn_mfma_f32_16x16x32_bf16(a[m], b[n], acc[m][n], 0,0,0);
  }
  int colb = bn*128 + wc*64;
  int rowb = bm*128 + wr*64;
  #pragma unroll
  for (int m=0;m<4;m++){
    int row0 = rowb + m*16 + (lane>>4)*4;
    #pragma unroll
    for (int n=0;n<4;n++){
      int col = colb + n*16 + (lane&15);
      float bv = bias[col];
      #pragma unroll
      for (int r2=0;r2<4;r2++){
        int row = row0 + r2;
        int orow = REMAP ? ((row&15)*SEQ + (row>>4)) : row;
        C[(size_t)orow*N + col] = acc[m][n][r2] + bv;
      }
    }
  }
}

// ---------------------------------------------------------------------------
// FUSED kernel: recurrence (WG 0..63, dataflow sentinel handshake) +
// Wout pack (WG 64..255, L3-direct stores) + logits GEMM workers (everyone,
// ticket queue gated on per-step production counter).
//
// Cross-XCD visibility intra-kernel: ALL producer->consumer global data uses
// agent-scope atomic (L3-direct) loads/stores. Normal cached reads of such
// data happen only AFTER a gate that proves the L3 copy is current (lines are
// first-touch this kernel; L2s are invalidated at kernel start).
// ---------------------------------------------------------------------------
__global__ __launch_bounds__(256,1) void lstm_fused(
    const u16* __restrict__ Whp, const float* __restrict__ Xpre,
    u16* hb, u16* Hp, u32* cnt, u32* tix, u32* packdone,
    const float* __restrict__ Wout, u16* __restrict__ Woutp,
    const float* __restrict__ bout, float* __restrict__ out)
{
  __shared__ char SMEM[148480];      // rec: smWf 128KB + gl 17KB; gemm: 16KB
  __shared__ u32 s_tick;
  u16* smWf = (u16*)SMEM;
  float (*gl)[16][17] = (float (*)[16][17])(SMEM + 131072);
  u16* sm = (u16*)SMEM;

  int tid = threadIdx.x; int lane = tid&63; int v = tid>>6;
  int w = blockIdx.x;

  if (w >= NWREC){
    // ---------------- Wout pack (L3-direct so workers on any XCD see it) ---
    const int NPK = (VOCAB/16)*(HIDDEN/32)*64;   // 4,096,000 fragments*lanes
    int u0 = (w - NWREC)*256 + tid;
    for (int u = u0; u < NPK; u += NWPACK*256){
      int l = u&63; int kb = (u>>6)&31; int nblk = u>>11;
      int col = nblk*16 + (l&15);
      int k0  = kb*32 + ((l>>4)<<3);
      u16x8 vv;
      #pragma unroll
      for (int e=0;e<8;e++) vv[e] = f2bf(Wout[(size_t)(k0+e)*VOCAB + col]);
      u64x2 t2 = __builtin_bit_cast(u64x2, vv);
      u64* dst = (u64*)(Woutp + (size_t)u*8);
      as64(dst+0, t2[0]);
      as64(dst+1, t2[1]);
    }
    asm volatile("s_waitcnt vmcnt(0)" ::: "memory");
    __syncthreads();
    if (tid==0) (void)__hip_atomic_fetch_add(packdone, 1u,
                       __ATOMIC_RELAXED, __HIP_MEMORY_SCOPE_AGENT);
  } else {
    // ---------------- recurrence (dataflow, no global barrier) ------------
    #pragma unroll
    for (int f=0; f<32; ++f){
      int frag = v*32 + f;
      int g = frag>>5, kc = frag&31;
      const u16* src = Whp + ((size_t)(g*64 + w)*32 + kc)*512 + lane*8;
      gload_lds16(src, smWf + (size_t)frag*512);
    }
    asm volatile("s_waitcnt vmcnt(0)" ::: "memory");
    __syncthreads();

    float c = 0.f;
    int pb = tid>>4, pj = tid&15;
    int j = w*16 + pj;
    const int a_row = lane&15, a_k = (lane>>4)*8;
    const float* xb0 = Xpre + (size_t)pb*GCOLS + j;
    float x0 = xb0[0], x1 = xb0[1024], x2 = xb0[2048], x3 = xb0[3072];

    for (int s=0;s<SEQ;s++){
      const u16* rbuf = hb + (size_t)s*16384;       // h entering step s
      // --- sentinel-poll A-fragments: the loads ARE the sync ---
      u64 vv[16];
      #pragma unroll
      for (int i=0;i<16;i++){
        const u64* p = (const u64*)(rbuf + a_row*1024 + (v*8+(i>>1))*32 + a_k) + (i&1);
        vv[i] = al64(p);
      }
      for(;;){
        bool ok = true;
        #pragma unroll
        for (int i=0;i<16;i++)
          if (((u32)vv[i]==SENT32) | ((u32)(vv[i]>>32)==SENT32)) ok = false;
        if (ok) break;
        __builtin_amdgcn_s_sleep(1);
        #pragma unroll
        for (int i=0;i<16;i++){
          if (((u32)vv[i]==SENT32) | ((u32)(vv[i]>>32)==SENT32)){
            const u64* p = (const u64*)(rbuf + a_row*1024 + (v*8+(i>>1))*32 + a_k) + (i&1);
            vv[i] = al64(p);
          }
        }
      }
      bf16x8 af[8];
      #pragma unroll
      for (int i=0;i<8;i++){
        u64x2 t2 = {vv[2*i], vv[2*i+1]};
        af[i] = __builtin_bit_cast(bf16x8, t2);
      }
      f32x4 acc[4] = {};
      #pragma unroll
      for (int i=0;i<8;i++){
        #pragma unroll
        for (int g=0;g<4;g++){
          bf16x8 wfv = *(const bf16x8*)(smWf + ((size_t)(g*32 + v*8 + i))*512 + lane*8);
          acc[g] = __builtin_amdgcn_mfma_f32_16x16x32_bf16(af[i], wfv, acc[g], 0,0,0);
        }
      }
      {
        int jj = lane&15, b0 = (lane>>4)*4;
        #pragma unroll
        for (int g=0;g<4;g++)
          #pragma unroll
          for (int r2=0;r2<4;r2++)
            gl[v*4+g][b0+r2][jj] = acc[g][r2];
      }
      __syncthreads();                               // B1 (intra-WG reduce)
      float p0 = x0 + gl[0][pb][pj] + gl[4][pb][pj] + gl[ 8][pb][pj] + gl[12][pb][pj];
      float p1 = x1 + gl[1][pb][pj] + gl[5][pb][pj] + gl[ 9][pb][pj] + gl[13][pb][pj];
      float p2 = x2 + gl[2][pb][pj] + gl[6][pb][pj] + gl[10][pb][pj] + gl[14][pb][pj];
      float p3 = x3 + gl[3][pb][pj] + gl[7][pb][pj] + gl[11][pb][pj] + gl[15][pb][pj];
      float fg = 1.f/(1.f+__expf(-p0));
      float ig = 1.f/(1.f+__expf(-p1));
      float e2 = __expf(2.f*fminf(fmaxf(p2,-15.f),15.f));
      float cand = (e2-1.f)/(e2+1.f);
      float og = 1.f/(1.f+__expf(-p3));
      c = c*fg + cand*ig;
      float h = c*og;                  // reference: h = c * o
      if (s < SEQ-1){
        const float* xn = Xpre + ((size_t)(s+1)*16 + pb)*GCOLS + j;
        x0 = xn[0]; x1 = xn[1024]; x2 = xn[2048]; x3 = xn[3072];
      }
      u32 hw_ = (u32)f2bf(h);
      u32 ow_ = (u32)__shfl_xor((int)hw_, 1);
      if ((pj&1)==0){
        u32 word = hw_ | (ow_<<16);
        if (s < SEQ-1){
          u16* wstep = hb + (size_t)(s+1)*16384;     // h leaving step s
          as32((u32*)wstep + (size_t)pb*512 + w*8 + (pj>>1), word);
        }
        as32((u32*)Hp + (size_t)s*8192 + (size_t)(j>>5)*256
                      + (size_t)(((j>>3)&3)*16 + pb)*4 + ((j&7)>>1), word);
      }
      asm volatile("s_waitcnt vmcnt(0)" ::: "memory");  // own stores at L3
      __syncthreads();                               // B2 (whole WG landed)
      if (tid==0)
        (void)__hip_atomic_fetch_add(cnt + (size_t)s*16, 1u,
                 __ATOMIC_RELAXED, __HIP_MEMORY_SCOPE_AGENT);
    }
  }

  // ---------------- everyone becomes a logits-GEMM worker -----------------
  if (tid==0){
    while (al32(packdone) < (u32)NWPACK) __builtin_amdgcn_s_sleep(2);
  }
  __syncthreads();

  int wv = tid>>6;
  int wr = wv>>1, wc = wv&1;
  for(;;){
    __syncthreads();
    if (tid==0) s_tick = __hip_atomic_fetch_add(tix, 1u,
                   __ATOMIC_RELAXED, __HIP_MEMORY_SCOPE_AGENT);
    __syncthreads();
    u32 t = s_tick;
    if (t >= (u32)NTILE) break;
    int bm = (int)(t/250u), bn = (int)(t%250u);
    if (tid==0){
      while (al32(cnt + (size_t)(bm*8+7)*16) < (u32)NWREC)
        __builtin_amdgcn_s_sleep(2);
    }
    __syncthreads();
    f32x4 acc[4][4] = {};
    const u16* Abase = Hp + (size_t)(bm*8)*32*512;
    const u16* Bbase = Woutp + (size_t)(bn*8)*32*512;
    for (int kb=0; kb<32; ++kb){
      __syncthreads();
      #pragma unroll
      for (int c2=0;c2<4;c2++){
        int chunk = wv*4 + c2;
        const u16* g;
        if (chunk < 8) g = Abase + ((size_t)chunk*32 + kb)*512 + lane*8;
        else           g = Bbase + ((size_t)(chunk-8)*32 + kb)*512 + lane*8;
        gload_lds16(g, sm + chunk*512);
      }
      __syncthreads();
      bf16x8 a[4], b[4];
      #pragma unroll
      for (int m=0;m<4;m++) a[m] = *(const bf16x8*)(sm + (wr*4+m)*512 + lane*8);
      #pragma unroll
      for (int n=0;n<4;n++) b[n] = *(const bf16x8*)(sm + 4096 + (wc*4+n)*512 + lane*8);
      #pragma unroll
      for (int m=0;m<4;m++)
        #pragma unroll
        for (int n=0;n<4;n++)
          acc[m][n] = __builtin_amdgcn_mfma_f32_16x16x32_bf16(a[m], b[n], acc[m][n], 0,0,0);
    }
    int colb = bn*128 + wc*64;
    int rowb = bm*128 + wr*64;
    #pragma unroll
    for (int m=0;m<4;m++){
      int row0 = rowb + m*16 + (lane>>4)*4;
      #pragma unroll
      for (int n=0;n<4;n++){
        int col = colb + n*16 + (lane&15);
        float bv = bout[col];
        #pragma unroll
        for (int r2=0;r2<4;r2++){
          int row = row0 + r2;
          int orow = (row&15)*SEQ + (row>>4);
          out[(size_t)orow*VOCAB + col] = acc[m][n][r2] + bv;
        }
      }
    }
  }
}

// ---------------------------------------------------------------------------
extern "C" void kernel_launch(void* const* d_in, const int* in_sizes, int n_in,
                              void* d_out, int out_size, void* d_ws, size_t ws_size,
                              hipStream_t stream)
{
  (void)in_sizes; (void)n_in; (void)out_size; (void)ws_size;
  const int*   tok   = (const int*)d_in[0];
  const float* embed = (const float*)d_in[1];
  const float* Wf    = (const float*)d_in[2];
  const float* bf_   = (const float*)d_in[3];
  const float* Wi    = (const float*)d_in[4];
  const float* bi_   = (const float*)d_in[5];
  const float* Wc    = (const float*)d_in[6];
  const float* bc_   = (const float*)d_in[7];
  const float* Wo    = (const float*)d_in[8];
  const float* bo_   = (const float*)d_in[9];
  const float* Wout  = (const float*)d_in[10];
  const float* bout  = (const float*)d_in[11];
  float* out = (float*)d_out;

  char* ws = (char*)d_ws;
  size_t off = 0;
  auto alloc = [&](size_t bytes)->void*{
    void* p = ws + off; off += (bytes + 255) & ~(size_t)255; return p;
  };
  // dead-after-gemm16 region first; hb aliases it (memset AFTER gemm16):
  u16*  Wxp   = (u16*)alloc((size_t)2097152*2);        // 4 MB
  u16*  Xg    = (u16*)alloc((size_t)2097152*2);        // 4 MB
  float* bcat = (float*)alloc((size_t)4096*4);         // 16 KB
  u16*  hb    = (u16*)ws;                              // 256 x 32KB = 8 MB alias
  // live-through-fused region:
  u16*  Whp   = (u16*)alloc((size_t)4194304*2);        // 8 MB
  u16*  Woutp = (u16*)alloc((size_t)32768000*2);       // 65.5 MB
  float* Xpre = (float*)alloc((size_t)NROW*GCOLS*4);   // 64 MB
  u16*  Hp    = (u16*)alloc((size_t)4194304*2);        // 8 MB
  u32*  cnt   = (u32*)alloc((size_t)256*64);           // 16 KB (64B/step)
  u32*  tix   = (u32*)alloc((size_t)256);
  u32*  packdone = (u32*)alloc((size_t)256);

  pack_gates<<<3088, 256, 0, stream>>>(Wf,Wi,Wc,Wo, bf_,bi_,bc_,bo_,
                                       Wxp, Whp, bcat);
  gather_kernel<<<1024, 256, 0, stream>>>(tok, embed, Xg);
  gemm_pk<16,false><<<1024, 256, 0, stream>>>(Xg, Wxp, bcat, Xpre, 32, GCOLS);
  // hb region (aliases Wxp/Xg/bcat) initialized only now that gemm16 is done:
  (void)hipMemsetAsync(hb, 0x00, 32768, stream);                    // h_0 = 0
  (void)hipMemsetAsync((char*)hb + 32768, 0xFF, 255*32768, stream); // sentinels
  (void)hipMemsetAsync(cnt, 0, 256*64 + 512, stream);               // cnt+tix+packdone
  lstm_fused<<<NWREC+NWPACK, 256, 0, stream>>>(Whp, Xpre, hb, Hp, cnt, tix,
                                               packdone, Wout, Woutp, bout, out);
}

// Round 9
// 1247.966 us; speedup vs baseline: 1.8709x; 1.0012x over previous
//
#include <hip/hip_runtime.h>
#include <hip/hip_bf16.h>

#define VOCAB  32000
#define EMBED  512
#define HIDDEN 1024
#define BATCH  16
#define SEQ    256
#define NROW   (BATCH*SEQ)
#define GCOLS  (4*HIDDEN)
#define NWREC  64
#define NWPACK 192
#define NTILE  8000          // 32 bm x 250 bn
#define SENT32 0xFFFFFFFFu

typedef unsigned short u16;
typedef unsigned int   u32;
typedef unsigned long long u64;
typedef __attribute__((ext_vector_type(4))) float f32x4;
typedef __attribute__((ext_vector_type(8))) short bf16x8;
typedef __attribute__((ext_vector_type(8))) unsigned short u16x8;
typedef __attribute__((ext_vector_type(2))) unsigned long long u64x2;

__device__ inline u16 f2bf(float f){
  __hip_bfloat16 h = __float2bfloat16(f);
  return __builtin_bit_cast(u16, h);
}
__device__ inline void gload_lds16(const void* g, void* l){
  __builtin_amdgcn_global_load_lds((const __attribute__((address_space(1))) u32*)g,
                                   (__attribute__((address_space(3))) u32*)l, 16, 0, 0);
}
__device__ __forceinline__ u32 al32(const u32* p){
  return __hip_atomic_load(p, __ATOMIC_RELAXED, __HIP_MEMORY_SCOPE_AGENT);
}
__device__ __forceinline__ u64 al64(const u64* p){
  return __hip_atomic_load(p, __ATOMIC_RELAXED, __HIP_MEMORY_SCOPE_AGENT);
}
__device__ __forceinline__ void as32(u32* p, u32 v){
  __hip_atomic_store(p, v, __ATOMIC_RELAXED, __HIP_MEMORY_SCOPE_AGENT);
}
__device__ __forceinline__ void as64(u64* p, u64 v){
  __hip_atomic_store(p, v, __ATOMIC_RELAXED, __HIP_MEMORY_SCOPE_AGENT);
}

// ---------------------------------------------------------------------------
__global__ __launch_bounds__(256) void pack_gates(
    const float* __restrict__ Wf, const float* __restrict__ Wi,
    const float* __restrict__ Wc, const float* __restrict__ Wo,
    const float* __restrict__ bf_, const float* __restrict__ bi_,
    const float* __restrict__ bc_, const float* __restrict__ bo_,
    u16* __restrict__ Wxp, u16* __restrict__ Whp, float* __restrict__ bcat)
{
  const int NT_WX = (GCOLS/16)*(EMBED/32)*64;
  const int NT_WH = (GCOLS/16)*(HIDDEN/32)*64;
  int t = blockIdx.x*256 + threadIdx.x;
  if (t < NT_WX){
    int u = t;
    int lane = u&63; int kb = (u>>6)&15; int nblk = u>>10;
    int col = nblk*16 + (lane&15);
    int k0  = kb*32 + ((lane>>4)<<3);
    int g = col>>10, j = col&1023;
    const float* W = (g==0)?Wf:(g==1)?Wi:(g==2)?Wc:Wo;
    u16x8 v;
    #pragma unroll
    for (int e=0;e<8;e++) v[e] = f2bf(W[(size_t)(k0+e)*HIDDEN + j]);
    *(u16x8*)(Wxp + (size_t)u*8) = v;
  } else if (t < NT_WX + NT_WH){
    int u = t - NT_WX;
    int lane = u&63; int kb = (u>>6)&31; int nblk = u>>11;
    int col = nblk*16 + (lane&15);
    int k0  = kb*32 + ((lane>>4)<<3);
    int g = col>>10, j = col&1023;
    const float* W = (g==0)?Wf:(g==1)?Wi:(g==2)?Wc:Wo;
    u16x8 v;
    #pragma unroll
    for (int e=0;e<8;e++) v[e] = f2bf(W[(size_t)(EMBED + k0+e)*HIDDEN + j]);
    *(u16x8*)(Whp + (size_t)u*8) = v;
  } else {
    int u = t - NT_WX - NT_WH;
    if (u < GCOLS){
      int g = u>>10, j = u&1023;
      const float* B = (g==0)?bf_:(g==1)?bi_:(g==2)?bc_:bo_;
      bcat[u] = B[j];
    }
  }
}

// ---------------------------------------------------------------------------
__global__ __launch_bounds__(256) void gather_kernel(
    const int* __restrict__ tok, const float* __restrict__ embed, u16* __restrict__ Xg)
{
  int t = blockIdx.x*256 + threadIdx.x;
  int lane = t&63; int kb = (t>>6)&15; int mblk = t>>10;
  int s = mblk; int b = lane&15;
  int token = tok[b*SEQ + s];
  int k0 = kb*32 + ((lane>>4)<<3);
  const float* src = embed + (size_t)token*EMBED + k0;
  u16x8 v;
  #pragma unroll
  for (int e=0;e<8;e++) v[e] = f2bf(src[e]);
  *(u16x8*)(Xg + (size_t)t*8) = v;
}

// ---------------------------------------------------------------------------
// 128x128 GEMM for the X-precompute (unchanged, 2 blocks/CU).
// ---------------------------------------------------------------------------
template<int KB, bool REMAP>
__global__ __launch_bounds__(256,2) void gemm_pk(
    const u16* __restrict__ Ap, const u16* __restrict__ Bp,
    const float* __restrict__ bias, float* __restrict__ C,
    int Nblk128, int N)
{
  __shared__ u16 sm[8192];
  int tid = threadIdx.x; int lane = tid&63; int wv = tid>>6;
  int nwg = gridDim.x;
  int bid = blockIdx.x;
  int swz = (bid&7)*(nwg>>3) + (bid>>3);
  int bm = swz / Nblk128, bn = swz % Nblk128;
  int wr = wv>>1, wc = wv&1;
  f32x4 acc[4][4] = {};
  const u16* Abase = Ap + (size_t)(bm*8)*KB*512;
  const u16* Bbase = Bp + (size_t)(bn*8)*KB*512;
  for (int kb=0; kb<KB; ++kb){
    __syncthreads();
    #pragma unroll
    for (int c2=0;c2<4;c2++){
      int chunk = wv*4 + c2;
      const u16* g;
      if (chunk < 8) g = Abase + ((size_t)chunk*KB + kb)*512 + lane*8;
      else           g = Bbase + ((size_t)(chunk-8)*KB + kb)*512 + lane*8;
      gload_lds16(g, sm + chunk*512);
    }
    __syncthreads();
    bf16x8 a[4], b[4];
    #pragma unroll
    for (int m=0;m<4;m++) a[m] = *(const bf16x8*)(sm + (wr*4+m)*512 + lane*8);
    #pragma unroll
    for (int n=0;n<4;n++) b[n] = *(const bf16x8*)(sm + 4096 + (wc*4+n)*512 + lane*8);
    #pragma unroll
    for (int m=0;m<4;m++)
      #pragma unroll
      for (int n=0;n<4;n++)
        acc[m][n] = __builtin_amdgcn_mfma_f32_16x16x32_bf16(a[m], b[n], acc[m][n], 0,0,0);
  }
  int colb = bn*128 + wc*64;
  int rowb = bm*128 + wr*64;
  #pragma unroll
  for (int m=0;m<4;m++){
    int row0 = rowb + m*16 + (lane>>4)*4;
    #pragma unroll
    for (int n=0;n<4;n++){
      int col = colb + n*16 + (lane&15);
      float bv = bias[col];
      #pragma unroll
      for (int r2=0;r2<4;r2++){
        int row = row0 + r2;
        int orow = REMAP ? ((row&15)*SEQ + (row>>4)) : row;
        C[(size_t)orow*N + col] = acc[m][n][r2] + bv;
      }
    }
  }
}

// ---------------------------------------------------------------------------
// FUSED: recurrence (WG 0..63, flag-hinted sentinel dataflow, per-8-step
// bookkeeping) + Wout pack (WG 64..255) + logits GEMM pool (3-buffer
// pipelined, counted vmcnt, raw barriers, nontemporal C-stores).
// ---------------------------------------------------------------------------
__global__ __launch_bounds__(256,1) void lstm_fused(
    const u16* __restrict__ Whp, const float* __restrict__ Xpre,
    u16* hb, u16* Hp, u32* cnt, u32* tix, u32* packdone, u32* fl,
    const float* __restrict__ Wout, u16* __restrict__ Woutp,
    const float* __restrict__ bout, float* __restrict__ out)
{
  __shared__ char SMEM[148480];
  __shared__ u32 s_tick;
  u16* smWf = (u16*)SMEM;
  float (*gl)[16][17] = (float (*)[16][17])(SMEM + 131072);
  u16* smg = (u16*)SMEM;             // GEMM phase: 3 x 16KB buffers

  int tid = threadIdx.x; int lane = tid&63; int v = tid>>6;
  int w = blockIdx.x;

  if (w >= NWREC){
    // ---------------- Wout pack (L3-direct stores) ------------------------
    const int NPK = (VOCAB/16)*(HIDDEN/32)*64;
    int u0 = (w - NWREC)*256 + tid;
    for (int u = u0; u < NPK; u += NWPACK*256){
      int l = u&63; int kb = (u>>6)&31; int nblk = u>>11;
      int col = nblk*16 + (l&15);
      int k0  = kb*32 + ((l>>4)<<3);
      u16x8 vv;
      #pragma unroll
      for (int e=0;e<8;e++) vv[e] = f2bf(Wout[(size_t)(k0+e)*VOCAB + col]);
      u64x2 t2 = __builtin_bit_cast(u64x2, vv);
      u64* dst = (u64*)(Woutp + (size_t)u*8);
      as64(dst+0, t2[0]);
      as64(dst+1, t2[1]);
    }
    asm volatile("s_waitcnt vmcnt(0)" ::: "memory");
    __syncthreads();
    if (tid==0) (void)__hip_atomic_fetch_add(packdone, 1u,
                       __ATOMIC_RELAXED, __HIP_MEMORY_SCOPE_AGENT);
  } else {
    // ---------------- recurrence ------------------------------------------
    #pragma unroll
    for (int f=0; f<32; ++f){
      int frag = v*32 + f;
      int g = frag>>5, kc = frag&31;
      const u16* src = Whp + ((size_t)(g*64 + w)*32 + kc)*512 + lane*8;
      gload_lds16(src, smWf + (size_t)frag*512);
    }
    asm volatile("s_waitcnt vmcnt(0)" ::: "memory");
    __syncthreads();

    float c = 0.f;
    int pb = tid>>4, pj = tid&15;
    int j = w*16 + pj;
    const int a_row = lane&15, a_k = (lane>>4)*8;
    const float* xb0 = Xpre + (size_t)pb*GCOLS + j;
    float x0 = xb0[0], x1 = xb0[1024], x2 = xb0[2048], x3 = xb0[3072];

    for (int s=0;s<SEQ;s++){
      const u16* rbuf = hb + (size_t)s*16384;
      // optimistic data loads; sentinel check; flag-poll fallback
      u64 vv[16];
      #pragma unroll
      for (int i=0;i<16;i++){
        const u64* p = (const u64*)(rbuf + a_row*1024 + (v*8+(i>>1))*32 + a_k) + (i&1);
        vv[i] = al64(p);
      }
      bool ok = true;
      #pragma unroll
      for (int i=0;i<16;i++)
        ok &= ((u32)vv[i]!=SENT32) & ((u32)(vv[i]>>32)!=SENT32);
      if (!ok){
        if (s > 0){
          const u32* fls = fl + (size_t)s*64;
          for(;;){
            u32 fv = al32(fls + lane);
            if (__all(fv != 0u)) break;
            __builtin_amdgcn_s_sleep(1);
          }
        }
        for(;;){
          #pragma unroll
          for (int i=0;i<16;i++){
            const u64* p = (const u64*)(rbuf + a_row*1024 + (v*8+(i>>1))*32 + a_k) + (i&1);
            vv[i] = al64(p);
          }
          bool ok2 = true;
          #pragma unroll
          for (int i=0;i<16;i++)
            ok2 &= ((u32)vv[i]!=SENT32) & ((u32)(vv[i]>>32)!=SENT32);
          if (ok2) break;
          __builtin_amdgcn_s_sleep(1);
        }
      }
      bf16x8 af[8];
      #pragma unroll
      for (int i=0;i<8;i++){
        u64x2 t2 = {vv[2*i], vv[2*i+1]};
        af[i] = __builtin_bit_cast(bf16x8, t2);
      }
      f32x4 acc[4] = {};
      #pragma unroll
      for (int i=0;i<8;i++){
        #pragma unroll
        for (int g=0;g<4;g++){
          bf16x8 wfv = *(const bf16x8*)(smWf + ((size_t)(g*32 + v*8 + i))*512 + lane*8);
          acc[g] = __builtin_amdgcn_mfma_f32_16x16x32_bf16(af[i], wfv, acc[g], 0,0,0);
        }
      }
      {
        int jj = lane&15, b0 = (lane>>4)*4;
        #pragma unroll
        for (int g=0;g<4;g++)
          #pragma unroll
          for (int r2=0;r2<4;r2++)
            gl[v*4+g][b0+r2][jj] = acc[g][r2];
      }
      __syncthreads();                               // B1
      float p0 = x0 + gl[0][pb][pj] + gl[4][pb][pj] + gl[ 8][pb][pj] + gl[12][pb][pj];
      float p1 = x1 + gl[1][pb][pj] + gl[5][pb][pj] + gl[ 9][pb][pj] + gl[13][pb][pj];
      float p2 = x2 + gl[2][pb][pj] + gl[6][pb][pj] + gl[10][pb][pj] + gl[14][pb][pj];
      float p3 = x3 + gl[3][pb][pj] + gl[7][pb][pj] + gl[11][pb][pj] + gl[15][pb][pj];
      float fg = 1.f/(1.f+__expf(-p0));
      float ig = 1.f/(1.f+__expf(-p1));
      float e2 = __expf(2.f*fminf(fmaxf(p2,-15.f),15.f));
      float cand = (e2-1.f)/(e2+1.f);
      float og = 1.f/(1.f+__expf(-p3));
      c = c*fg + cand*ig;
      float h = c*og;
      if (s < SEQ-1){
        const float* xn = Xpre + ((size_t)(s+1)*16 + pb)*GCOLS + j;
        x0 = xn[0]; x1 = xn[1024]; x2 = xn[2048]; x3 = xn[3072];
      }
      u32 hw_ = (u32)f2bf(h);
      u32 ow_ = (u32)__shfl_xor((int)hw_, 1);
      if ((pj&1)==0){
        u32 word = hw_ | (ow_<<16);
        if (s < SEQ-1){
          u16* wstep = hb + (size_t)(s+1)*16384;
          as32((u32*)wstep + (size_t)pb*512 + w*8 + (pj>>1), word);
        }
        as32((u32*)Hp + (size_t)s*8192 + (size_t)(j>>5)*256
                      + (size_t)(((j>>3)&3)*16 + pb)*4 + ((j&7)>>1), word);
      }
      __syncthreads();                               // B2: stores issued, gl WAR
      if (tid==0 && s < SEQ-1)
        as32(fl + (size_t)(s+1)*64 + w, 1u);         // flag (no ack wait!)
      if ((s&7)==7){                                 // per-8-step bookkeeping
        asm volatile("s_waitcnt vmcnt(0)" ::: "memory");
        __syncthreads();                             // B3
        if (tid==0)
          (void)__hip_atomic_fetch_add(cnt + (size_t)(s>>3)*16, 1u,
                   __ATOMIC_RELAXED, __HIP_MEMORY_SCOPE_AGENT);
      }
    }
  }

  // ---------------- logits-GEMM worker pool -------------------------------
  if (tid==0){
    while (al32(packdone) < (u32)NWPACK) __builtin_amdgcn_s_sleep(2);
  }
  __syncthreads();

  int wv = tid>>6;
  int wr = wv>>1, wc = wv&1;
  for(;;){
    __syncthreads();
    if (tid==0) s_tick = __hip_atomic_fetch_add(tix, 1u,
                   __ATOMIC_RELAXED, __HIP_MEMORY_SCOPE_AGENT);
    __syncthreads();
    u32 t = s_tick;
    if (t >= (u32)NTILE) break;
    int bm = (int)(t/250u), bn = (int)(t%250u);
    if (tid==0){
      while (al32(cnt + (size_t)bm*16) < (u32)NWREC)
        __builtin_amdgcn_s_sleep(2);
    }
    __syncthreads();                                 // full drain (vm+lgkm)
    const u16* Ab = Hp + (size_t)(bm*8)*32*512;
    const u16* Bb = Woutp + (size_t)(bn*8)*32*512;
    auto stage = [&](int kb, int bi){
      #pragma unroll
      for (int c2=0;c2<4;c2++){
        int chunk = wv*4 + c2;
        const u16* g;
        if (chunk < 8) g = Ab + ((size_t)chunk*32 + kb)*512 + lane*8;
        else           g = Bb + ((size_t)(chunk-8)*32 + kb)*512 + lane*8;
        gload_lds16(g, smg + (size_t)bi*8192 + chunk*512);
      }
    };
    stage(0,0); stage(1,1);
    f32x4 acc[4][4] = {};
    for (int kb=0; kb<32; ++kb){
      if (kb<31) asm volatile("s_waitcnt vmcnt(4)" ::: "memory");
      else       asm volatile("s_waitcnt vmcnt(0)" ::: "memory");
      __builtin_amdgcn_s_barrier();                  // raw: loads stay in flight
      if (kb+2<32) stage(kb+2, (kb+2)%3);
      const u16* bufp = smg + (size_t)(kb%3)*8192;
      bf16x8 a[4], b[4];
      #pragma unroll
      for (int m=0;m<4;m++) a[m] = *(const bf16x8*)(bufp + (wr*4+m)*512 + lane*8);
      #pragma unroll
      for (int n=0;n<4;n++) b[n] = *(const bf16x8*)(bufp + 4096 + (wc*4+n)*512 + lane*8);
      #pragma unroll
      for (int m=0;m<4;m++)
        #pragma unroll
        for (int n=0;n<4;n++)
          acc[m][n] = __builtin_amdgcn_mfma_f32_16x16x32_bf16(a[m], b[n], acc[m][n], 0,0,0);
    }
    int colb = bn*128 + wc*64;
    int rowb = bm*128 + wr*64;
    #pragma unroll
    for (int m=0;m<4;m++){
      int row0 = rowb + m*16 + (lane>>4)*4;
      #pragma unroll
      for (int n=0;n<4;n++){
        int col = colb + n*16 + (lane&15);
        float bv = bout[col];
        #pragma unroll
        for (int r2=0;r2<4;r2++){
          int row = row0 + r2;
          int orow = (row&15)*SEQ + (row>>4);
          __builtin_nontemporal_store(acc[m][n][r2] + bv,
                                      &out[(size_t)orow*VOCAB + col]);
        }
      }
    }
  }
}

// ---------------------------------------------------------------------------
extern "C" void kernel_launch(void* const* d_in, const int* in_sizes, int n_in,
                              void* d_out, int out_size, void* d_ws, size_t ws_size,
                              hipStream_t stream)
{
  (void)in_sizes; (void)n_in; (void)out_size; (void)ws_size;
  const int*   tok   = (const int*)d_in[0];
  const float* embed = (const float*)d_in[1];
  const float* Wf    = (const float*)d_in[2];
  const float* bf_   = (const float*)d_in[3];
  const float* Wi    = (const float*)d_in[4];
  const float* bi_   = (const float*)d_in[5];
  const float* Wc    = (const float*)d_in[6];
  const float* bc_   = (const float*)d_in[7];
  const float* Wo    = (const float*)d_in[8];
  const float* bo_   = (const float*)d_in[9];
  const float* Wout  = (const float*)d_in[10];
  const float* bout  = (const float*)d_in[11];
  float* out = (float*)d_out;

  char* ws = (char*)d_ws;
  size_t off = 0;
  auto alloc = [&](size_t bytes)->void*{
    void* p = ws + off; off += (bytes + 255) & ~(size_t)255; return p;
  };
  // dead-after-gemm16 region; hb aliases it (memset AFTER gemm16):
  u16*  Wxp   = (u16*)alloc((size_t)2097152*2);        // 4 MB
  u16*  Xg    = (u16*)alloc((size_t)2097152*2);        // 4 MB
  float* bcat = (float*)alloc((size_t)4096*4);         // 16 KB
  u16*  hb    = (u16*)ws;                              // 256 x 32KB = 8 MB alias
  // live-through-fused region:
  u16*  Whp   = (u16*)alloc((size_t)4194304*2);        // 8 MB
  u16*  Woutp = (u16*)alloc((size_t)32768000*2);       // 65.5 MB
  float* Xpre = (float*)alloc((size_t)NROW*GCOLS*4);   // 64 MB
  u16*  Hp    = (u16*)alloc((size_t)4194304*2);        // 8 MB
  u32*  cnt   = (u32*)alloc((size_t)4096);             // 32 bm x 64B
  u32*  tix   = (u32*)alloc((size_t)256);
  u32*  packdone = (u32*)alloc((size_t)256);
  u32*  fl    = (u32*)alloc((size_t)SEQ*64*4);         // 64 KB flags

  pack_gates<<<3088, 256, 0, stream>>>(Wf,Wi,Wc,Wo, bf_,bi_,bc_,bo_,
                                       Wxp, Whp, bcat);
  gather_kernel<<<1024, 256, 0, stream>>>(tok, embed, Xg);
  gemm_pk<16,false><<<1024, 256, 0, stream>>>(Xg, Wxp, bcat, Xpre, 32, GCOLS);
  // hb aliases Wxp/Xg -> init only after gemm16:
  (void)hipMemsetAsync(hb, 0x00, 32768, stream);                    // h_0 = 0
  (void)hipMemsetAsync((char*)hb + 32768, 0xFF, 255*32768, stream); // sentinels
  (void)hipMemsetAsync(cnt, 0, 4096 + 256 + 256 + SEQ*64*4, stream);
  lstm_fused<<<NWREC+NWPACK, 256, 0, stream>>>(Whp, Xpre, hb, Hp, cnt, tix,
                                               packdone, fl, Wout, Woutp, bout, out);
}

// Round 10
// 1169.455 us; speedup vs baseline: 1.9965x; 1.0671x over previous
//
#include <hip/hip_runtime.h>
#include <hip/hip_bf16.h>

#define VOCAB  32000
#define EMBED  512
#define HIDDEN 1024
#define BATCH  16
#define SEQ    256
#define NROW   (BATCH*SEQ)
#define GCOLS  (4*HIDDEN)
#define NWREC  64
#define NWPACK 192
#define NTILE  8000          // 32 bm x 250 bn
#define SENT32 0xFFFFFFFFu

typedef unsigned short u16;
typedef unsigned int   u32;
typedef unsigned long long u64;
typedef __attribute__((ext_vector_type(4))) float f32x4;
typedef __attribute__((ext_vector_type(8))) short bf16x8;
typedef __attribute__((ext_vector_type(8))) unsigned short u16x8;
typedef __attribute__((ext_vector_type(2))) unsigned long long u64x2;

__device__ inline u16 f2bf(float f){
  __hip_bfloat16 h = __float2bfloat16(f);
  return __builtin_bit_cast(u16, h);
}
__device__ inline void gload_lds16(const void* g, void* l){
  __builtin_amdgcn_global_load_lds((const __attribute__((address_space(1))) u32*)g,
                                   (__attribute__((address_space(3))) u32*)l, 16, 0, 0);
}
__device__ __forceinline__ u32 al32(const u32* p){
  return __hip_atomic_load(p, __ATOMIC_RELAXED, __HIP_MEMORY_SCOPE_AGENT);
}
__device__ __forceinline__ u64 al64(const u64* p){
  return __hip_atomic_load(p, __ATOMIC_RELAXED, __HIP_MEMORY_SCOPE_AGENT);
}
__device__ __forceinline__ void as32(u32* p, u32 v){
  __hip_atomic_store(p, v, __ATOMIC_RELAXED, __HIP_MEMORY_SCOPE_AGENT);
}
__device__ __forceinline__ void as64(u64* p, u64 v){
  __hip_atomic_store(p, v, __ATOMIC_RELAXED, __HIP_MEMORY_SCOPE_AGENT);
}

// ---------------------------------------------------------------------------
__global__ __launch_bounds__(256) void pack_gates(
    const float* __restrict__ Wf, const float* __restrict__ Wi,
    const float* __restrict__ Wc, const float* __restrict__ Wo,
    const float* __restrict__ bf_, const float* __restrict__ bi_,
    const float* __restrict__ bc_, const float* __restrict__ bo_,
    u16* __restrict__ Wxp, u16* __restrict__ Whp, float* __restrict__ bcat)
{
  const int NT_WX = (GCOLS/16)*(EMBED/32)*64;
  const int NT_WH = (GCOLS/16)*(HIDDEN/32)*64;
  int t = blockIdx.x*256 + threadIdx.x;
  if (t < NT_WX){
    int u = t;
    int lane = u&63; int kb = (u>>6)&15; int nblk = u>>10;
    int col = nblk*16 + (lane&15);
    int k0  = kb*32 + ((lane>>4)<<3);
    int g = col>>10, j = col&1023;
    const float* W = (g==0)?Wf:(g==1)?Wi:(g==2)?Wc:Wo;
    u16x8 v;
    #pragma unroll
    for (int e=0;e<8;e++) v[e] = f2bf(W[(size_t)(k0+e)*HIDDEN + j]);
    *(u16x8*)(Wxp + (size_t)u*8) = v;
  } else if (t < NT_WX + NT_WH){
    int u = t - NT_WX;
    int lane = u&63; int kb = (u>>6)&31; int nblk = u>>11;
    int col = nblk*16 + (lane&15);
    int k0  = kb*32 + ((lane>>4)<<3);
    int g = col>>10, j = col&1023;
    const float* W = (g==0)?Wf:(g==1)?Wi:(g==2)?Wc:Wo;
    u16x8 v;
    #pragma unroll
    for (int e=0;e<8;e++) v[e] = f2bf(W[(size_t)(EMBED + k0+e)*HIDDEN + j]);
    *(u16x8*)(Whp + (size_t)u*8) = v;
  } else {
    int u = t - NT_WX - NT_WH;
    if (u < GCOLS){
      int g = u>>10, j = u&1023;
      const float* B = (g==0)?bf_:(g==1)?bi_:(g==2)?bc_:bo_;
      bcat[u] = B[j];
    }
  }
}

// ---------------------------------------------------------------------------
__global__ __launch_bounds__(256) void gather_kernel(
    const int* __restrict__ tok, const float* __restrict__ embed, u16* __restrict__ Xg)
{
  int t = blockIdx.x*256 + threadIdx.x;
  int lane = t&63; int kb = (t>>6)&15; int mblk = t>>10;
  int s = mblk; int b = lane&15;
  int token = tok[b*SEQ + s];
  int k0 = kb*32 + ((lane>>4)<<3);
  const float* src = embed + (size_t)token*EMBED + k0;
  u16x8 v;
  #pragma unroll
  for (int e=0;e<8;e++) v[e] = f2bf(src[e]);
  *(u16x8*)(Xg + (size_t)t*8) = v;
}

// ---------------------------------------------------------------------------
// 128x128 GEMM for the X-precompute.
// ---------------------------------------------------------------------------
template<int KB, bool REMAP>
__global__ __launch_bounds__(256,2) void gemm_pk(
    const u16* __restrict__ Ap, const u16* __restrict__ Bp,
    const float* __restrict__ bias, float* __restrict__ C,
    int Nblk128, int N)
{
  __shared__ u16 sm[8192];
  int tid = threadIdx.x; int lane = tid&63; int wv = tid>>6;
  int nwg = gridDim.x;
  int bid = blockIdx.x;
  int swz = (bid&7)*(nwg>>3) + (bid>>3);
  int bm = swz / Nblk128, bn = swz % Nblk128;
  int wr = wv>>1, wc = wv&1;
  f32x4 acc[4][4] = {};
  const u16* Abase = Ap + (size_t)(bm*8)*KB*512;
  const u16* Bbase = Bp + (size_t)(bn*8)*KB*512;
  for (int kb=0; kb<KB; ++kb){
    __syncthreads();
    #pragma unroll
    for (int c2=0;c2<4;c2++){
      int chunk = wv*4 + c2;
      const u16* g;
      if (chunk < 8) g = Abase + ((size_t)chunk*KB + kb)*512 + lane*8;
      else           g = Bbase + ((size_t)(chunk-8)*KB + kb)*512 + lane*8;
      gload_lds16(g, sm + chunk*512);
    }
    __syncthreads();
    bf16x8 a[4], b[4];
    #pragma unroll
    for (int m=0;m<4;m++) a[m] = *(const bf16x8*)(sm + (wr*4+m)*512 + lane*8);
    #pragma unroll
    for (int n=0;n<4;n++) b[n] = *(const bf16x8*)(sm + 4096 + (wc*4+n)*512 + lane*8);
    #pragma unroll
    for (int m=0;m<4;m++)
      #pragma unroll
      for (int n=0;n<4;n++)
        acc[m][n] = __builtin_amdgcn_mfma_f32_16x16x32_bf16(a[m], b[n], acc[m][n], 0,0,0);
  }
  int colb = bn*128 + wc*64;
  int rowb = bm*128 + wr*64;
  #pragma unroll
  for (int m=0;m<4;m++){
    int row0 = rowb + m*16 + (lane>>4)*4;
    #pragma unroll
    for (int n=0;n<4;n++){
      int col = colb + n*16 + (lane&15);
      float bv = bias[col];
      #pragma unroll
      for (int r2=0;r2<4;r2++){
        int row = row0 + r2;
        int orow = REMAP ? ((row&15)*SEQ + (row>>4)) : row;
        C[(size_t)orow*N + col] = acc[m][n][r2] + bv;
      }
    }
  }
}

// ---------------------------------------------------------------------------
// FUSED: recurrence with RAW-BARRIER step loop (no vmcnt drains on the step
// chain — the round-7/8/9 pace was the implicit s_waitcnt vmcnt(0) hipcc
// emits before every __syncthreads) + Wout pack + pipelined logits GEMM pool.
// Sync = pure data-sentinel polling; h stores are fire-and-forget.
// ---------------------------------------------------------------------------
__global__ __launch_bounds__(256,1) void lstm_fused(
    const u16* __restrict__ Whp, const float* __restrict__ Xpre,
    u16* hb, u16* Hp, u32* cnt, u32* tix, u32* packdone,
    const float* __restrict__ Wout, u16* __restrict__ Woutp,
    const float* __restrict__ bout, float* __restrict__ out)
{
  __shared__ char SMEM[148480];
  __shared__ u32 s_tick;
  u16* smWf = (u16*)SMEM;
  float (*gl)[16][17] = (float (*)[16][17])(SMEM + 131072);
  u16* smg = (u16*)SMEM;             // GEMM phase: 3 x 16KB buffers

  int tid = threadIdx.x; int lane = tid&63; int v = tid>>6;
  int w = blockIdx.x;

  if (w >= NWREC){
    // ---------------- Wout pack (L3-direct stores) ------------------------
    const int NPK = (VOCAB/16)*(HIDDEN/32)*64;
    int u0 = (w - NWREC)*256 + tid;
    for (int u = u0; u < NPK; u += NWPACK*256){
      int l = u&63; int kb = (u>>6)&31; int nblk = u>>11;
      int col = nblk*16 + (l&15);
      int k0  = kb*32 + ((l>>4)<<3);
      u16x8 vv;
      #pragma unroll
      for (int e=0;e<8;e++) vv[e] = f2bf(Wout[(size_t)(k0+e)*VOCAB + col]);
      u64x2 t2 = __builtin_bit_cast(u64x2, vv);
      u64* dst = (u64*)(Woutp + (size_t)u*8);
      as64(dst+0, t2[0]);
      as64(dst+1, t2[1]);
    }
    asm volatile("s_waitcnt vmcnt(0)" ::: "memory");
    __syncthreads();
    if (tid==0) (void)__hip_atomic_fetch_add(packdone, 1u,
                       __ATOMIC_RELAXED, __HIP_MEMORY_SCOPE_AGENT);
  } else {
    // ---------------- recurrence ------------------------------------------
    #pragma unroll
    for (int f=0; f<32; ++f){
      int frag = v*32 + f;
      int g = frag>>5, kc = frag&31;
      const u16* src = Whp + ((size_t)(g*64 + w)*32 + kc)*512 + lane*8;
      gload_lds16(src, smWf + (size_t)frag*512);
    }
    asm volatile("s_waitcnt vmcnt(0)" ::: "memory");
    __syncthreads();

    float c = 0.f;
    int pb = tid>>4, pj = tid&15;
    int j = w*16 + pj;
    const int a_row = lane&15, a_k = (lane>>4)*8;
    const float* xb0 = Xpre + (size_t)pb*GCOLS + j;
    float x0 = xb0[0], x1 = xb0[1024], x2 = xb0[2048], x3 = xb0[3072];

    for (int s=0;s<SEQ;s++){
      const u16* rbuf = hb + (size_t)s*16384;
      // --- data-sentinel poll: the loads ARE the sync (no flags, no acks) ---
      u64 vv[16];
      for(;;){
        #pragma unroll
        for (int i=0;i<16;i++){
          const u64* p = (const u64*)(rbuf + a_row*1024 + (v*8+(i>>1))*32 + a_k) + (i&1);
          vv[i] = al64(p);
        }
        bool ok = true;
        #pragma unroll
        for (int i=0;i<16;i++)
          ok &= ((u32)vv[i]!=SENT32) & ((u32)(vv[i]>>32)!=SENT32);
        if (ok) break;
        __builtin_amdgcn_s_sleep(1);
      }
      bf16x8 af[8];
      #pragma unroll
      for (int i=0;i<8;i++){
        u64x2 t2 = {vv[2*i], vv[2*i+1]};
        af[i] = __builtin_bit_cast(bf16x8, t2);
      }
      f32x4 acc[4] = {};
      #pragma unroll
      for (int i=0;i<8;i++){
        #pragma unroll
        for (int g=0;g<4;g++){
          bf16x8 wfv = *(const bf16x8*)(smWf + ((size_t)(g*32 + v*8 + i))*512 + lane*8);
          acc[g] = __builtin_amdgcn_mfma_f32_16x16x32_bf16(af[i], wfv, acc[g], 0,0,0);
        }
      }
      {
        int jj = lane&15, b0 = (lane>>4)*4;
        #pragma unroll
        for (int g=0;g<4;g++)
          #pragma unroll
          for (int r2=0;r2<4;r2++)
            gl[v*4+g][b0+r2][jj] = acc[g][r2];
      }
      // B1: LDS-only drain + RAW barrier (NO vmcnt drain)
      asm volatile("s_waitcnt lgkmcnt(0)" ::: "memory");
      __builtin_amdgcn_s_barrier();
      __builtin_amdgcn_sched_barrier(0);
      // x-prefetch for s+1 (independent; overlaps pointwise + next poll)
      float xn0=0.f,xn1=0.f,xn2=0.f,xn3=0.f;
      if (s < SEQ-1){
        const float* xn = Xpre + ((size_t)(s+1)*16 + pb)*GCOLS + j;
        xn0 = xn[0]; xn1 = xn[1024]; xn2 = xn[2048]; xn3 = xn[3072];
      }
      float p0 = x0 + gl[0][pb][pj] + gl[4][pb][pj] + gl[ 8][pb][pj] + gl[12][pb][pj];
      float p1 = x1 + gl[1][pb][pj] + gl[5][pb][pj] + gl[ 9][pb][pj] + gl[13][pb][pj];
      float p2 = x2 + gl[2][pb][pj] + gl[6][pb][pj] + gl[10][pb][pj] + gl[14][pb][pj];
      float p3 = x3 + gl[3][pb][pj] + gl[7][pb][pj] + gl[11][pb][pj] + gl[15][pb][pj];
      float fg = 1.f/(1.f+__expf(-p0));
      float ig = 1.f/(1.f+__expf(-p1));
      float e2 = __expf(2.f*fminf(fmaxf(p2,-15.f),15.f));
      float cand = (e2-1.f)/(e2+1.f);
      float og = 1.f/(1.f+__expf(-p3));
      c = c*fg + cand*ig;
      float h = c*og;
      x0 = xn0; x1 = xn1; x2 = xn2; x3 = xn3;
      u32 hw_ = (u32)f2bf(h);
      u32 ow_ = (u32)__shfl_xor((int)hw_, 1);
      if ((pj&1)==0){
        u32 word = hw_ | (ow_<<16);
        if (s < SEQ-1){
          u16* wstep = hb + (size_t)(s+1)*16384;
          as32((u32*)wstep + (size_t)pb*512 + w*8 + (pj>>1), word);  // fire & forget
        }
        as32((u32*)Hp + (size_t)s*8192 + (size_t)(j>>5)*256
                      + (size_t)(((j>>3)&3)*16 + pb)*4 + ((j&7)>>1), word);
      }
      // B2: RAW barrier only (gl WAR ordering; ds_reads already in registers)
      __builtin_amdgcn_s_barrier();
      __builtin_amdgcn_sched_barrier(0);
      if ((s&7)==7){
        // per-8-step bookkeeping: the ONLY store-ack wait on the chain
        asm volatile("s_waitcnt vmcnt(0)" ::: "memory");
        __builtin_amdgcn_s_barrier();
        asm volatile("" ::: "memory");
        if (tid==0)
          (void)__hip_atomic_fetch_add(cnt + (size_t)(s>>3)*16, 1u,
                   __ATOMIC_RELAXED, __HIP_MEMORY_SCOPE_AGENT);
      }
    }
  }

  // ---------------- logits-GEMM worker pool -------------------------------
  if (tid==0){
    while (al32(packdone) < (u32)NWPACK) __builtin_amdgcn_s_sleep(2);
  }
  __syncthreads();

  int wv = tid>>6;
  int wr = wv>>1, wc = wv&1;
  for(;;){
    __syncthreads();
    if (tid==0) s_tick = __hip_atomic_fetch_add(tix, 1u,
                   __ATOMIC_RELAXED, __HIP_MEMORY_SCOPE_AGENT);
    __syncthreads();
    u32 t = s_tick;
    if (t >= (u32)NTILE) break;
    int bm = (int)(t/250u), bn = (int)(t%250u);
    if (tid==0){
      while (al32(cnt + (size_t)bm*16) < (u32)NWREC)
        __builtin_amdgcn_s_sleep(2);
    }
    __syncthreads();                                 // full drain (vm+lgkm)
    const u16* Ab = Hp + (size_t)(bm*8)*32*512;
    const u16* Bb = Woutp + (size_t)(bn*8)*32*512;
    auto stage = [&](int kb, int bi){
      #pragma unroll
      for (int c2=0;c2<4;c2++){
        int chunk = wv*4 + c2;
        const u16* g;
        if (chunk < 8) g = Ab + ((size_t)chunk*32 + kb)*512 + lane*8;
        else           g = Bb + ((size_t)(chunk-8)*32 + kb)*512 + lane*8;
        gload_lds16(g, smg + (size_t)bi*8192 + chunk*512);
      }
    };
    stage(0,0); stage(1,1);
    f32x4 acc[4][4] = {};
    for (int kb=0; kb<32; ++kb){
      if (kb<31) asm volatile("s_waitcnt vmcnt(4)" ::: "memory");
      else       asm volatile("s_waitcnt vmcnt(0)" ::: "memory");
      __builtin_amdgcn_s_barrier();                  // raw: loads stay in flight
      if (kb+2<32) stage(kb+2, (kb+2)%3);
      const u16* bufp = smg + (size_t)(kb%3)*8192;
      bf16x8 a[4], b[4];
      #pragma unroll
      for (int m=0;m<4;m++) a[m] = *(const bf16x8*)(bufp + (wr*4+m)*512 + lane*8);
      #pragma unroll
      for (int n=0;n<4;n++) b[n] = *(const bf16x8*)(bufp + 4096 + (wc*4+n)*512 + lane*8);
      #pragma unroll
      for (int m=0;m<4;m++)
        #pragma unroll
        for (int n=0;n<4;n++)
          acc[m][n] = __builtin_amdgcn_mfma_f32_16x16x32_bf16(a[m], b[n], acc[m][n], 0,0,0);
    }
    int colb = bn*128 + wc*64;
    int rowb = bm*128 + wr*64;
    #pragma unroll
    for (int m=0;m<4;m++){
      int row0 = rowb + m*16 + (lane>>4)*4;
      #pragma unroll
      for (int n=0;n<4;n++){
        int col = colb + n*16 + (lane&15);
        float bv = bout[col];
        #pragma unroll
        for (int r2=0;r2<4;r2++){
          int row = row0 + r2;
          int orow = (row&15)*SEQ + (row>>4);
          __builtin_nontemporal_store(acc[m][n][r2] + bv,
                                      &out[(size_t)orow*VOCAB + col]);
        }
      }
    }
  }
}

// ---------------------------------------------------------------------------
extern "C" void kernel_launch(void* const* d_in, const int* in_sizes, int n_in,
                              void* d_out, int out_size, void* d_ws, size_t ws_size,
                              hipStream_t stream)
{
  (void)in_sizes; (void)n_in; (void)out_size; (void)ws_size;
  const int*   tok   = (const int*)d_in[0];
  const float* embed = (const float*)d_in[1];
  const float* Wf    = (const float*)d_in[2];
  const float* bf_   = (const float*)d_in[3];
  const float* Wi    = (const float*)d_in[4];
  const float* bi_   = (const float*)d_in[5];
  const float* Wc    = (const float*)d_in[6];
  const float* bc_   = (const float*)d_in[7];
  const float* Wo    = (const float*)d_in[8];
  const float* bo_   = (const float*)d_in[9];
  const float* Wout  = (const float*)d_in[10];
  const float* bout  = (const float*)d_in[11];
  float* out = (float*)d_out;

  char* ws = (char*)d_ws;
  size_t off = 0;
  auto alloc = [&](size_t bytes)->void*{
    void* p = ws + off; off += (bytes + 255) & ~(size_t)255; return p;
  };
  // dead-after-gemm16 region; hb aliases it (memset AFTER gemm16):
  u16*  Wxp   = (u16*)alloc((size_t)2097152*2);        // 4 MB
  u16*  Xg    = (u16*)alloc((size_t)2097152*2);        // 4 MB
  float* bcat = (float*)alloc((size_t)4096*4);         // 16 KB
  u16*  hb    = (u16*)ws;                              // 256 x 32KB = 8 MB alias
  // live-through-fused region:
  u16*  Whp   = (u16*)alloc((size_t)4194304*2);        // 8 MB
  u16*  Woutp = (u16*)alloc((size_t)32768000*2);       // 65.5 MB
  float* Xpre = (float*)alloc((size_t)NROW*GCOLS*4);   // 64 MB
  u16*  Hp    = (u16*)alloc((size_t)4194304*2);        // 8 MB
  u32*  cnt   = (u32*)alloc((size_t)4096);             // 32 bm x 64B
  u32*  tix   = (u32*)alloc((size_t)256);
  u32*  packdone = (u32*)alloc((size_t)256);

  pack_gates<<<3088, 256, 0, stream>>>(Wf,Wi,Wc,Wo, bf_,bi_,bc_,bo_,
                                       Wxp, Whp, bcat);
  gather_kernel<<<1024, 256, 0, stream>>>(tok, embed, Xg);
  gemm_pk<16,false><<<1024, 256, 0, stream>>>(Xg, Wxp, bcat, Xpre, 32, GCOLS);
  // hb aliases Wxp/Xg -> init only after gemm16:
  (void)hipMemsetAsync(hb, 0x00, 32768, stream);                    // h_0 = 0
  (void)hipMemsetAsync((char*)hb + 32768, 0xFF, 255*32768, stream); // sentinels
  (void)hipMemsetAsync(cnt, 0, 4096 + 256 + 256, stream);
  lstm_fused<<<NWREC+NWPACK, 256, 0, stream>>>(Whp, Xpre, hb, Hp, cnt, tix,
                                               packdone, Wout, Woutp, bout, out);
}